// Round 13
// baseline (181.691 us; speedup 1.0000x reference)
//
#include <hip/hip_runtime.h>

// R13 = STORE-ONLY PROBE round: R12 byte-identical + one extra kernel that
// replays conv's exact NT store pattern with no loads/compute (writes zeros;
// the real conv overwrites -> output correct). dur_us - 106.7 = t_storeonly.

#define BB 32
#define HH 224
#define WW 224
#define CC 3
#define FF 64
#define NPIX (BB * HH * WW)          // 1,605,632

// padded median buffer: [32][226][228], zero borders
#define PH 226
#define PW 228
#define PB (PH * PW)
#define NPAD (BB * PB)

typedef float f32x4 __attribute__((ext_vector_type(4)));
typedef float f32x4u __attribute__((ext_vector_type(4), aligned(4)));

// compare-exchange: A=min, B=max
#define CEX(A,B) { const float _lo = fminf(A,B); B = fmaxf(A,B); A = _lo; }

// ---- PROBE: conv's store pattern, no loads ---------------------------------
__global__ __launch_bounds__(256) void store_probe_kernel(float* __restrict__ out) {
    const int bid = blockIdx.x;                 // 7168
    const int h  = bid % HH;
    const int b  = bid / HH;
    const int fg = threadIdx.x & 15;
    const int pg = threadIdx.x >> 4;
    const int f4 = fg * 4;

    float* orow = out + (((long long)b * HH + h) * WW) * FF + f4;
    const f32x4 z = {0.f, 0.f, 0.f, 0.f};
    #pragma unroll
    for (int it = 0; it < 7; ++it) {
        const int p = it * 32 + pg * 2;
        float* op = orow + (long long)p * FF;
        __builtin_nontemporal_store(z, (f32x4*)op);
        __builtin_nontemporal_store(z, (f32x4*)(op + FF));
    }
}

// ---- Kernel 1: median via shared sorted columns, LDS-staged input ----------
__global__ __launch_bounds__(128) void median_pad_kernel(const float* __restrict__ x,
                                                         float* __restrict__ cmed,
                                                         float* __restrict__ partial) {
    const int bid = blockIdx.x;                // 32 * 56 = 1792
    const int b  = bid / 56;
    const int hg = bid % 56;
    const int lr = threadIdx.x >> 5;           // local output row 0..3
    const int s  = threadIdx.x & 31;
    const int w0 = s * 7;
    const int h  = hg * 4 + lr;

    __shared__ float xs[6][680];               // rows hg*4-1 .. hg*4+4; 16.3 KB
    {
        const int h0 = hg * 4 - 1;
        for (int t = threadIdx.x; t < 1008; t += 128) {   // 6 rows x 168 chunks
            const int rr = t / 168, i = t % 168;
            const int hin = h0 + rr;
            f32x4 v = {0.f, 0.f, 0.f, 0.f};
            if (hin >= 0 && hin < HH) {
                v = *(const f32x4*)(x + (((long long)b * HH + hin) * WW) * CC + i * 4);
            }
            *(f32x4*)&xs[rr][4 + i * 4] = v;   // 16B-aligned LDS write
        }
        if (threadIdx.x < 48) {                // zero halo cols: dwords 0..3, 676..679
            const int rr = threadIdx.x >> 3, k = threadIdx.x & 7;
            xs[rr][(k < 4) ? k : (672 + k)] = 0.f;
        }
    }
    __syncthreads();

    float col[9][9];                           // static indices only (macros)

#define COLSTEP(CS) { \
    const int cb = 4 + (w0 - 1 + (CS)) * 3; \
    float a0 = xs[lr][cb+0],   a1 = xs[lr][cb+1],   a2 = xs[lr][cb+2]; \
    float b0 = xs[lr+1][cb+0], b1 = xs[lr+1][cb+1], b2 = xs[lr+1][cb+2]; \
    float c0 = xs[lr+2][cb+0], c1 = xs[lr+2][cb+1], c2 = xs[lr+2][cb+2]; \
    CEX(a0,a1); CEX(a1,a2); CEX(a0,a1); \
    CEX(b0,b1); CEX(b1,b2); CEX(b0,b1); \
    CEX(c0,c1); CEX(c1,c2); CEX(c0,c1); \
    float s0 = a0, L = b0; CEX(s0, L); \
    float s5 = b2, Hh = a2; CEX(Hh, s5); \
    float q0 = L, q1 = a1, q2 = b1, q3 = Hh; \
    CEX(q0,q1); CEX(q2,q3); CEX(q0,q2); CEX(q1,q3); CEX(q1,q2); \
    float z0 = s0, p = c0; CEX(z0, p); \
    float z8 = c2, qq = s5; CEX(qq, z8); \
    float t0 = p, t1 = c1, t2 = qq; CEX(t0,t1); CEX(t1,t2); CEX(t0,t1); \
    float m1 = q0, u = t0; CEX(m1, u); \
    float m7 = t2, vvv = q3; CEX(vvv, m7); \
    float e0 = u, e1 = q1, e2 = q2; CEX(e0,e1); CEX(e1,e2); \
    float f0 = t1, f1 = e0, f2 = e1, f3 = e2; CEX(f0,f1); CEX(f1,f2); CEX(f2,f3); \
    float g0 = vvv, g1 = f0, g2 = f1, g3 = f2, g4 = f3; \
    CEX(g0,g1); CEX(g1,g2); CEX(g2,g3); CEX(g3,g4); \
    col[CS][0]=z0; col[CS][1]=m1; col[CS][2]=g0; col[CS][3]=g1; col[CS][4]=g2; \
    col[CS][5]=g3; col[CS][6]=g4; col[CS][7]=m7; col[CS][8]=z8; }

    COLSTEP(0) COLSTEP(1) COLSTEP(2) COLSTEP(3) COLSTEP(4)
    COLSTEP(5) COLSTEP(6) COLSTEP(7) COLSTEP(8)

    float med[7];
    float lsum = 0.f;

#define MEDSTEP(O) { \
    float x0 = col[O][0], y0 = col[O+2][0]; CEX(x0, y0); \
    float x8 = col[O][8], y8 = col[O+2][8]; CEX(x8, y8); \
    float g0 = y0, g1 = col[O][1], g2 = col[O][2], g3 = col[O][3], \
          g4 = col[O][4], g5 = col[O][5], g6 = col[O][6], g7 = col[O][7]; \
    CEX(g0,g1); CEX(g1,g2); CEX(g2,g3); CEX(g3,g4); CEX(g4,g5); CEX(g5,g6); CEX(g6,g7); \
    float h0 = col[O+2][1], h1 = col[O+2][2], h2 = col[O+2][3], h3 = col[O+2][4], \
          h4 = col[O+2][5], h5 = col[O+2][6], h6 = col[O+2][7], h7 = x8; \
    CEX(h6,h7); CEX(h5,h6); CEX(h4,h5); CEX(h3,h4); CEX(h2,h3); CEX(h1,h2); CEX(h0,h1); \
    float Ea = g0, Eb = g4, Ec = h0, Ed = h4; \
    float Ea2 = g2, Eb2 = g6, Ec2 = h2, Ed2 = h6; \
    CEX(Ea,Ec); CEX(Eb,Ed); CEX(Eb,Ec); \
    CEX(Ea2,Ec2); CEX(Eb2,Ed2); CEX(Eb2,Ec2); \
    CEX(Ea2,Eb); CEX(Eb2,Ec); CEX(Ec2,Ed); \
    float Fa = g1, Fb = g5, Fc = h1, Fd = h5; \
    float Fa2 = g3, Fb2 = g7, Fc2 = h3, Fd2 = h7; \
    CEX(Fa,Fc); CEX(Fb,Fd); CEX(Fb,Fc); \
    CEX(Fa2,Fc2); CEX(Fb2,Fd2); CEX(Fb2,Fc2); \
    CEX(Fa2,Fb); CEX(Fb2,Fc); CEX(Fc2,Fd); \
    float M3 = Fa2, M4 = Eb;  CEX(M3, M4); \
    float M5 = Fb,  M6 = Eb2; CEX(M5, M6); \
    float M7 = Fb2, M8 = Ec;  CEX(M7, M8); \
    float M9 = Fc,  M10 = Ec2; CEX(M9, M10); \
    float M11 = Fc2, M12 = Ed; CEX(M11, M12); \
    float r = fminf(fmaxf(M3, col[O+1][8]), fmaxf(M4, col[O+1][7])); \
    r = fminf(r, fmaxf(M5, col[O+1][6])); \
    r = fminf(r, fmaxf(M6, col[O+1][5])); \
    r = fminf(r, fmaxf(M7, col[O+1][4])); \
    r = fminf(r, fmaxf(M8, col[O+1][3])); \
    r = fminf(r, fmaxf(M9, col[O+1][2])); \
    r = fminf(r, fmaxf(M10, col[O+1][1])); \
    r = fminf(r, fmaxf(M11, col[O+1][0])); \
    r = fminf(r, M12); \
    med[O] = r; lsum += r; }

    MEDSTEP(0) MEDSTEP(1) MEDSTEP(2) MEDSTEP(3) MEDSTEP(4) MEDSTEP(5) MEDSTEP(6)

    float* crow = cmed + ((long long)b * PH + (h + 1)) * PW + (w0 + 1);
    crow[0] = med[0]; crow[1] = med[1]; crow[2] = med[2]; crow[3] = med[3];
    crow[4] = med[4]; crow[5] = med[5]; crow[6] = med[6];

    __shared__ float sdata[128];
    sdata[threadIdx.x] = lsum;
    __syncthreads();
    #pragma unroll
    for (int st = 64; st > 0; st >>= 1) {
        if (threadIdx.x < st) sdata[threadIdx.x] += sdata[threadIdx.x + st];
        __syncthreads();
    }
    if (threadIdx.x == 0) partial[blockIdx.x] = sdata[0];
}

// ---- Kernel 2: mean + Asum (block 0) + cmed border zeroing ------------------
__global__ __launch_bounds__(256) void mean_wsum_border_kernel(const float* __restrict__ partial,
                                                               const float* __restrict__ Wt,
                                                               float* __restrict__ mean_out,
                                                               float* __restrict__ Asum,
                                                               float* __restrict__ cmed) {
    if (blockIdx.x == 0) {
        if (threadIdx.x < FF) {
            float s = 0.0f;
            #pragma unroll
            for (int t = 0; t < 9; ++t) s += Wt[t * FF + threadIdx.x];
            Asum[threadIdx.x] = s;
        }
        float s = 0.0f;
        for (int i = threadIdx.x; i < 1792; i += 256) s += partial[i];
        __shared__ float sdata[256];
        sdata[threadIdx.x] = s;
        __syncthreads();
        #pragma unroll
        for (int st = 128; st > 0; st >>= 1) {
            if (threadIdx.x < st) sdata[threadIdx.x] += sdata[threadIdx.x + st];
            __syncthreads();
        }
        if (threadIdx.x == 0) mean_out[0] = sdata[0] / (float)NPIX;
    } else {
        const int u = (blockIdx.x - 1) * 256 + threadIdx.x;
        int b, hp, wp;
        if (u < 14592) {
            b = u / 456;
            const int v = u % 456;
            hp = (v < 228) ? 0 : (PH - 1);
            wp = (v < 228) ? v : (v - 228);
        } else {
            const int u2 = u - 14592;
            b = u2 / 896;
            const int v2 = u2 % 896;
            hp = 1 + (v2 % 224);
            const int j = v2 / 224;
            wp = (j == 0) ? 0 : (224 + j);
        }
        cmed[((long long)b * PH + hp) * PW + wp] = 0.0f;
    }
}

// ---- Kernel 3: row-persistent conv, ALL-LOADS-FIRST (byte-identical to R8) --
__global__ __launch_bounds__(256) void conv_kernel(const float* __restrict__ cmed,
                                                   const float* __restrict__ Wt,
                                                   const float* __restrict__ Asum,
                                                   const float* __restrict__ mean_p,
                                                   float* __restrict__ out) {
    const int bid = blockIdx.x;                 // 32*224 = 7168
    const int h  = bid % HH;
    const int b  = bid / HH;

    const int fg = threadIdx.x & 15;
    const int pg = threadIdx.x >> 4;
    const int f4 = fg * 4;

    float w[9][4];
    #pragma unroll
    for (int t = 0; t < 9; ++t) {
        const f32x4u wv = *(const f32x4u*)(Wt + t * FF + f4);
        w[t][0] = wv.x; w[t][1] = wv.y; w[t][2] = wv.z; w[t][3] = wv.w;
    }
    const f32x4u Av = *(const f32x4u*)(Asum + f4);
    const float mean = mean_p[0];

    const float* base = cmed + ((long long)b * PH + h) * PW;
    f32x4u cv[7][3];
    #pragma unroll
    for (int it = 0; it < 7; ++it) {
        #pragma unroll
        for (int r = 0; r < 3; ++r) {
            cv[it][r] = *(const f32x4u*)(base + r * PW + it * 32 + pg * 2);
        }
    }

    float Sb[4] = {Av.x, Av.y, Av.z, Av.w};
    if (h == 0) {
        #pragma unroll
        for (int k = 0; k < 4; ++k) Sb[k] -= (w[0][k] + w[1][k] + w[2][k]);
    }
    if (h == HH - 1) {
        #pragma unroll
        for (int k = 0; k < 4; ++k) Sb[k] -= (w[6][k] + w[7][k] + w[8][k]);
    }

    float* orow = out + (((long long)b * HH + h) * WW) * FF + f4;

    #pragma unroll
    for (int it = 0; it < 7; ++it) {
        const int p = it * 32 + pg * 2;

        float acc0[4] = {0.f, 0.f, 0.f, 0.f};
        float acc1[4] = {0.f, 0.f, 0.f, 0.f};
        #pragma unroll
        for (int r = 0; r < 3; ++r) {
            const f32x4u cvv = cv[it][r];
            #pragma unroll
            for (int k = 0; k < 4; ++k) {
                acc0[k] = fmaf(cvv.x, w[r * 3 + 0][k], acc0[k]);
                acc0[k] = fmaf(cvv.y, w[r * 3 + 1][k], acc0[k]);
                acc0[k] = fmaf(cvv.z, w[r * 3 + 2][k], acc0[k]);
                acc1[k] = fmaf(cvv.y, w[r * 3 + 0][k], acc1[k]);
                acc1[k] = fmaf(cvv.z, w[r * 3 + 1][k], acc1[k]);
                acc1[k] = fmaf(cvv.w, w[r * 3 + 2][k], acc1[k]);
            }
        }

        float S0[4], S1[4];
        #pragma unroll
        for (int k = 0; k < 4; ++k) { S0[k] = Sb[k]; S1[k] = Sb[k]; }
        if (it == 0 && pg == 0) {
            #pragma unroll
            for (int k = 0; k < 4; ++k) {
                S0[k] -= (w[0][k] + w[3][k] + w[6][k]);
                if (h == 0)      S0[k] += w[0][k];
                if (h == HH - 1) S0[k] += w[6][k];
            }
        }
        if (it == 6 && pg == 15) {
            #pragma unroll
            for (int k = 0; k < 4; ++k) {
                S1[k] -= (w[2][k] + w[5][k] + w[8][k]);
                if (h == 0)      S1[k] += w[2][k];
                if (h == HH - 1) S1[k] += w[8][k];
            }
        }

        f32x4 o0, o1;
        o0.x = fmaf(-mean, S0[0], acc0[0]); o0.y = fmaf(-mean, S0[1], acc0[1]);
        o0.z = fmaf(-mean, S0[2], acc0[2]); o0.w = fmaf(-mean, S0[3], acc0[3]);
        o1.x = fmaf(-mean, S1[0], acc1[0]); o1.y = fmaf(-mean, S1[1], acc1[1]);
        o1.z = fmaf(-mean, S1[2], acc1[2]); o1.w = fmaf(-mean, S1[3], acc1[3]);

        float* op = orow + (long long)p * FF;
        __builtin_nontemporal_store(o0, (f32x4*)op);
        __builtin_nontemporal_store(o1, (f32x4*)(op + FF));
    }
}

extern "C" void kernel_launch(void* const* d_in, const int* in_sizes, int n_in,
                              void* d_out, int out_size, void* d_ws, size_t ws_size,
                              hipStream_t stream) {
    const float* x  = (const float*)d_in[0];   // [32,224,224,3]
    const float* Wt = (const float*)d_in[1];   // [3,3,1,64]
    float* out = (float*)d_out;                // [32,224,224,64]

    float* cmed    = (float*)d_ws;             // NPAD floats, 16B aligned
    float* Asum    = cmed + NPAD;              // 64 floats
    float* partial = Asum + FF;                // 1792 floats
    float* mean_p  = partial + 1792;           // 1 float

    // PROBE: conv store pattern, no loads; real conv overwrites afterwards.
    store_probe_kernel<<<BB * HH, 256, 0, stream>>>(out);

    median_pad_kernel<<<1792, 128, 0, stream>>>(x, cmed, partial);
    mean_wsum_border_kernel<<<170, 256, 0, stream>>>(partial, Wt, mean_p, Asum, cmed);
    conv_kernel<<<BB * HH, 256, 0, stream>>>(cmed, Wt, Asum, mean_p, out);
}

// Round 14
// 105.647 us; speedup vs baseline: 1.7198x; 1.7198x over previous
//
#include <hip/hip_runtime.h>

#define BB 32
#define HH 224
#define WW 224
#define CC 3
#define FF 64
#define NPIX (BB * HH * WW)          // 1,605,632

// padded median buffer: [32][226][228], zero borders
#define PH 226
#define PW 228
#define PB (PH * PW)
#define NPAD (BB * PB)

typedef float f32x4 __attribute__((ext_vector_type(4)));
typedef float f32x4u __attribute__((ext_vector_type(4), aligned(4)));

// compare-exchange: A=min, B=max
#define CEX(A,B) { const float _lo = fminf(A,B); B = fmaxf(A,B); A = _lo; }

// ---- Kernel 1: median via shared sorted columns, LDS-staged input ----------
// (byte-identical to R12)
__global__ __launch_bounds__(128) void median_pad_kernel(const float* __restrict__ x,
                                                         float* __restrict__ cmed,
                                                         float* __restrict__ partial) {
    const int bid = blockIdx.x;                // 32 * 56 = 1792
    const int b  = bid / 56;
    const int hg = bid % 56;
    const int lr = threadIdx.x >> 5;           // local output row 0..3
    const int s  = threadIdx.x & 31;
    const int w0 = s * 7;
    const int h  = hg * 4 + lr;

    __shared__ float xs[6][680];               // rows hg*4-1 .. hg*4+4; 16.3 KB
    {
        const int h0 = hg * 4 - 1;
        for (int t = threadIdx.x; t < 1008; t += 128) {   // 6 rows x 168 chunks
            const int rr = t / 168, i = t % 168;
            const int hin = h0 + rr;
            f32x4 v = {0.f, 0.f, 0.f, 0.f};
            if (hin >= 0 && hin < HH) {
                v = *(const f32x4*)(x + (((long long)b * HH + hin) * WW) * CC + i * 4);
            }
            *(f32x4*)&xs[rr][4 + i * 4] = v;   // 16B-aligned LDS write
        }
        if (threadIdx.x < 48) {                // zero halo cols: dwords 0..3, 676..679
            const int rr = threadIdx.x >> 3, k = threadIdx.x & 7;
            xs[rr][(k < 4) ? k : (672 + k)] = 0.f;
        }
    }
    __syncthreads();

    float col[9][9];                           // static indices only (macros)

#define COLSTEP(CS) { \
    const int cb = 4 + (w0 - 1 + (CS)) * 3; \
    float a0 = xs[lr][cb+0],   a1 = xs[lr][cb+1],   a2 = xs[lr][cb+2]; \
    float b0 = xs[lr+1][cb+0], b1 = xs[lr+1][cb+1], b2 = xs[lr+1][cb+2]; \
    float c0 = xs[lr+2][cb+0], c1 = xs[lr+2][cb+1], c2 = xs[lr+2][cb+2]; \
    CEX(a0,a1); CEX(a1,a2); CEX(a0,a1); \
    CEX(b0,b1); CEX(b1,b2); CEX(b0,b1); \
    CEX(c0,c1); CEX(c1,c2); CEX(c0,c1); \
    float s0 = a0, L = b0; CEX(s0, L); \
    float s5 = b2, Hh = a2; CEX(Hh, s5); \
    float q0 = L, q1 = a1, q2 = b1, q3 = Hh; \
    CEX(q0,q1); CEX(q2,q3); CEX(q0,q2); CEX(q1,q3); CEX(q1,q2); \
    float z0 = s0, p = c0; CEX(z0, p); \
    float z8 = c2, qq = s5; CEX(qq, z8); \
    float t0 = p, t1 = c1, t2 = qq; CEX(t0,t1); CEX(t1,t2); CEX(t0,t1); \
    float m1 = q0, u = t0; CEX(m1, u); \
    float m7 = t2, vvv = q3; CEX(vvv, m7); \
    float e0 = u, e1 = q1, e2 = q2; CEX(e0,e1); CEX(e1,e2); \
    float f0 = t1, f1 = e0, f2 = e1, f3 = e2; CEX(f0,f1); CEX(f1,f2); CEX(f2,f3); \
    float g0 = vvv, g1 = f0, g2 = f1, g3 = f2, g4 = f3; \
    CEX(g0,g1); CEX(g1,g2); CEX(g2,g3); CEX(g3,g4); \
    col[CS][0]=z0; col[CS][1]=m1; col[CS][2]=g0; col[CS][3]=g1; col[CS][4]=g2; \
    col[CS][5]=g3; col[CS][6]=g4; col[CS][7]=m7; col[CS][8]=z8; }

    COLSTEP(0) COLSTEP(1) COLSTEP(2) COLSTEP(3) COLSTEP(4)
    COLSTEP(5) COLSTEP(6) COLSTEP(7) COLSTEP(8)

    float med[7];
    float lsum = 0.f;

#define MEDSTEP(O) { \
    float x0 = col[O][0], y0 = col[O+2][0]; CEX(x0, y0); \
    float x8 = col[O][8], y8 = col[O+2][8]; CEX(x8, y8); \
    float g0 = y0, g1 = col[O][1], g2 = col[O][2], g3 = col[O][3], \
          g4 = col[O][4], g5 = col[O][5], g6 = col[O][6], g7 = col[O][7]; \
    CEX(g0,g1); CEX(g1,g2); CEX(g2,g3); CEX(g3,g4); CEX(g4,g5); CEX(g5,g6); CEX(g6,g7); \
    float h0 = col[O+2][1], h1 = col[O+2][2], h2 = col[O+2][3], h3 = col[O+2][4], \
          h4 = col[O+2][5], h5 = col[O+2][6], h6 = col[O+2][7], h7 = x8; \
    CEX(h6,h7); CEX(h5,h6); CEX(h4,h5); CEX(h3,h4); CEX(h2,h3); CEX(h1,h2); CEX(h0,h1); \
    float Ea = g0, Eb = g4, Ec = h0, Ed = h4; \
    float Ea2 = g2, Eb2 = g6, Ec2 = h2, Ed2 = h6; \
    CEX(Ea,Ec); CEX(Eb,Ed); CEX(Eb,Ec); \
    CEX(Ea2,Ec2); CEX(Eb2,Ed2); CEX(Eb2,Ec2); \
    CEX(Ea2,Eb); CEX(Eb2,Ec); CEX(Ec2,Ed); \
    float Fa = g1, Fb = g5, Fc = h1, Fd = h5; \
    float Fa2 = g3, Fb2 = g7, Fc2 = h3, Fd2 = h7; \
    CEX(Fa,Fc); CEX(Fb,Fd); CEX(Fb,Fc); \
    CEX(Fa2,Fc2); CEX(Fb2,Fd2); CEX(Fb2,Fc2); \
    CEX(Fa2,Fb); CEX(Fb2,Fc); CEX(Fc2,Fd); \
    float M3 = Fa2, M4 = Eb;  CEX(M3, M4); \
    float M5 = Fb,  M6 = Eb2; CEX(M5, M6); \
    float M7 = Fb2, M8 = Ec;  CEX(M7, M8); \
    float M9 = Fc,  M10 = Ec2; CEX(M9, M10); \
    float M11 = Fc2, M12 = Ed; CEX(M11, M12); \
    float r = fminf(fmaxf(M3, col[O+1][8]), fmaxf(M4, col[O+1][7])); \
    r = fminf(r, fmaxf(M5, col[O+1][6])); \
    r = fminf(r, fmaxf(M6, col[O+1][5])); \
    r = fminf(r, fmaxf(M7, col[O+1][4])); \
    r = fminf(r, fmaxf(M8, col[O+1][3])); \
    r = fminf(r, fmaxf(M9, col[O+1][2])); \
    r = fminf(r, fmaxf(M10, col[O+1][1])); \
    r = fminf(r, fmaxf(M11, col[O+1][0])); \
    r = fminf(r, M12); \
    med[O] = r; lsum += r; }

    MEDSTEP(0) MEDSTEP(1) MEDSTEP(2) MEDSTEP(3) MEDSTEP(4) MEDSTEP(5) MEDSTEP(6)

    float* crow = cmed + ((long long)b * PH + (h + 1)) * PW + (w0 + 1);
    crow[0] = med[0]; crow[1] = med[1]; crow[2] = med[2]; crow[3] = med[3];
    crow[4] = med[4]; crow[5] = med[5]; crow[6] = med[6];

    __shared__ float sdata[128];
    sdata[threadIdx.x] = lsum;
    __syncthreads();
    #pragma unroll
    for (int st = 64; st > 0; st >>= 1) {
        if (threadIdx.x < st) sdata[threadIdx.x] += sdata[threadIdx.x + st];
        __syncthreads();
    }
    if (threadIdx.x == 0) partial[blockIdx.x] = sdata[0];
}

// ---- Kernel 2: mean + Asum (block 0) + cmed border zeroing ------------------
// (byte-identical to R12)
__global__ __launch_bounds__(256) void mean_wsum_border_kernel(const float* __restrict__ partial,
                                                               const float* __restrict__ Wt,
                                                               float* __restrict__ mean_out,
                                                               float* __restrict__ Asum,
                                                               float* __restrict__ cmed) {
    if (blockIdx.x == 0) {
        if (threadIdx.x < FF) {
            float s = 0.0f;
            #pragma unroll
            for (int t = 0; t < 9; ++t) s += Wt[t * FF + threadIdx.x];
            Asum[threadIdx.x] = s;
        }
        float s = 0.0f;
        for (int i = threadIdx.x; i < 1792; i += 256) s += partial[i];
        __shared__ float sdata[256];
        sdata[threadIdx.x] = s;
        __syncthreads();
        #pragma unroll
        for (int st = 128; st > 0; st >>= 1) {
            if (threadIdx.x < st) sdata[threadIdx.x] += sdata[threadIdx.x + st];
            __syncthreads();
        }
        if (threadIdx.x == 0) mean_out[0] = sdata[0] / (float)NPIX;
    } else {
        const int u = (blockIdx.x - 1) * 256 + threadIdx.x;
        int b, hp, wp;
        if (u < 14592) {
            b = u / 456;
            const int v = u % 456;
            hp = (v < 228) ? 0 : (PH - 1);
            wp = (v < 228) ? v : (v - 228);
        } else {
            const int u2 = u - 14592;
            b = u2 / 896;
            const int v2 = u2 % 896;
            hp = 1 + (v2 % 224);
            const int j = v2 / 224;
            wp = (j == 0) ? 0 : (224 + j);
        }
        cmed[((long long)b * PH + hp) * PW + wp] = 0.0f;
    }
}

// ---- Kernel 3: row-persistent conv, ALL-LOADS-FIRST, PLAIN stores ----------
// R13 probe: NT store-only = 75us (5.35 TB/s) vs fill's plain 6.8 TB/s ->
// the NT flag itself bypasses L2 write-combining and caps the stream. With
// all-loads-first, cmed loads complete before the first store, so plain
// stores' L2 pollution only exposes later blocks' 6.6MB cmed re-reads (~3us).
__global__ __launch_bounds__(256) void conv_kernel(const float* __restrict__ cmed,
                                                   const float* __restrict__ Wt,
                                                   const float* __restrict__ Asum,
                                                   const float* __restrict__ mean_p,
                                                   float* __restrict__ out) {
    const int bid = blockIdx.x;                 // 32*224 = 7168
    const int h  = bid % HH;
    const int b  = bid / HH;

    const int fg = threadIdx.x & 15;
    const int pg = threadIdx.x >> 4;
    const int f4 = fg * 4;

    float w[9][4];
    #pragma unroll
    for (int t = 0; t < 9; ++t) {
        const f32x4u wv = *(const f32x4u*)(Wt + t * FF + f4);
        w[t][0] = wv.x; w[t][1] = wv.y; w[t][2] = wv.z; w[t][3] = wv.w;
    }
    const f32x4u Av = *(const f32x4u*)(Asum + f4);
    const float mean = mean_p[0];

    const float* base = cmed + ((long long)b * PH + h) * PW;
    f32x4u cv[7][3];
    #pragma unroll
    for (int it = 0; it < 7; ++it) {
        #pragma unroll
        for (int r = 0; r < 3; ++r) {
            cv[it][r] = *(const f32x4u*)(base + r * PW + it * 32 + pg * 2);
        }
    }

    float Sb[4] = {Av.x, Av.y, Av.z, Av.w};
    if (h == 0) {
        #pragma unroll
        for (int k = 0; k < 4; ++k) Sb[k] -= (w[0][k] + w[1][k] + w[2][k]);
    }
    if (h == HH - 1) {
        #pragma unroll
        for (int k = 0; k < 4; ++k) Sb[k] -= (w[6][k] + w[7][k] + w[8][k]);
    }

    float* orow = out + (((long long)b * HH + h) * WW) * FF + f4;

    #pragma unroll
    for (int it = 0; it < 7; ++it) {
        const int p = it * 32 + pg * 2;

        float acc0[4] = {0.f, 0.f, 0.f, 0.f};
        float acc1[4] = {0.f, 0.f, 0.f, 0.f};
        #pragma unroll
        for (int r = 0; r < 3; ++r) {
            const f32x4u cvv = cv[it][r];
            #pragma unroll
            for (int k = 0; k < 4; ++k) {
                acc0[k] = fmaf(cvv.x, w[r * 3 + 0][k], acc0[k]);
                acc0[k] = fmaf(cvv.y, w[r * 3 + 1][k], acc0[k]);
                acc0[k] = fmaf(cvv.z, w[r * 3 + 2][k], acc0[k]);
                acc1[k] = fmaf(cvv.y, w[r * 3 + 0][k], acc1[k]);
                acc1[k] = fmaf(cvv.z, w[r * 3 + 1][k], acc1[k]);
                acc1[k] = fmaf(cvv.w, w[r * 3 + 2][k], acc1[k]);
            }
        }

        float S0[4], S1[4];
        #pragma unroll
        for (int k = 0; k < 4; ++k) { S0[k] = Sb[k]; S1[k] = Sb[k]; }
        if (it == 0 && pg == 0) {
            #pragma unroll
            for (int k = 0; k < 4; ++k) {
                S0[k] -= (w[0][k] + w[3][k] + w[6][k]);
                if (h == 0)      S0[k] += w[0][k];
                if (h == HH - 1) S0[k] += w[6][k];
            }
        }
        if (it == 6 && pg == 15) {
            #pragma unroll
            for (int k = 0; k < 4; ++k) {
                S1[k] -= (w[2][k] + w[5][k] + w[8][k]);
                if (h == 0)      S1[k] += w[2][k];
                if (h == HH - 1) S1[k] += w[8][k];
            }
        }

        f32x4 o0, o1;
        o0.x = fmaf(-mean, S0[0], acc0[0]); o0.y = fmaf(-mean, S0[1], acc0[1]);
        o0.z = fmaf(-mean, S0[2], acc0[2]); o0.w = fmaf(-mean, S0[3], acc0[3]);
        o1.x = fmaf(-mean, S1[0], acc1[0]); o1.y = fmaf(-mean, S1[1], acc1[1]);
        o1.z = fmaf(-mean, S1[2], acc1[2]); o1.w = fmaf(-mean, S1[3], acc1[3]);

        float* op = orow + (long long)p * FF;   // 16B aligned
        *(f32x4*)op = o0;                        // PLAIN stores (L2 write-combine)
        *(f32x4*)(op + FF) = o1;
    }
}

extern "C" void kernel_launch(void* const* d_in, const int* in_sizes, int n_in,
                              void* d_out, int out_size, void* d_ws, size_t ws_size,
                              hipStream_t stream) {
    const float* x  = (const float*)d_in[0];   // [32,224,224,3]
    const float* Wt = (const float*)d_in[1];   // [3,3,1,64]
    float* out = (float*)d_out;                // [32,224,224,64]

    float* cmed    = (float*)d_ws;             // NPAD floats, 16B aligned
    float* Asum    = cmed + NPAD;              // 64 floats
    float* partial = Asum + FF;                // 1792 floats
    float* mean_p  = partial + 1792;           // 1 float

    median_pad_kernel<<<1792, 128, 0, stream>>>(x, cmed, partial);
    mean_wsum_border_kernel<<<170, 256, 0, stream>>>(partial, Wt, mean_p, Asum, cmed);
    conv_kernel<<<BB * HH, 256, 0, stream>>>(cmed, Wt, Asum, mean_p, out);
}